// Round 9
// baseline (48.624 us; speedup 1.0000x reference)
//
#include <hip/hip_runtime.h>

// Problem constants: B,D,K,CI,CO,L,NB,P,S = 4,32,8,2,2,4096,15,7,8
constexpr int Bc  = 4;
constexpr int Dc  = 32;
constexpr int Kc  = 8;
constexpr int CIc = 2;
constexpr int COc = 2;
constexpr int Lc  = 4096;
constexpr int NBc = 15;
constexpr int Sc  = 8;

constexpr int NTHREADS = 256;
constexpr int JT       = 8;                  // outputs per thread per co
constexpr int TILE     = NTHREADS * JT;      // 2048 l per block
constexpr int WELEMS   = COc * CIc * Sc * NBc;  // 480
constexpr int WIN      = JT + 16;            // 24-float x window per ci

typedef float f32x4 __attribute__((ext_vector_type(4)));

// seg(l) = min(l/499, 7)
__device__ __forceinline__ int seg_of(int l) {
    int s = l / 499;
    return s > 7 ? 7 : s;
}

// launch_bounds(256, 5): 5 waves/SIMD min -> VGPR cap 102. Frees latency hiding;
// weight values are re-read from LDS (broadcast) instead of living in 32 VGPRs.
__global__ __launch_bounds__(NTHREADS, 5) void cde_bcr_kernel(
    const float* __restrict__ x,     // [B][D][K][CI][L]
    const float* __restrict__ w,     // [D][K][CO][CI][S][1][NB]
    const float* __restrict__ bias,  // [D][K][CO][S][1]
    float* __restrict__ out)         // [B][D][K][CO][L]
{
    __shared__ __align__(16) float wl[COc * CIc * Sc][16]; // row=(o*CI+i)*S+s
    __shared__ float bl[COc * Sc];

    const int tid   = threadIdx.x;
    const int lbase = blockIdx.x * TILE;
    const int bdk   = blockIdx.y;            // ((b*D + d)*K + k)
    const int dk    = bdk % (Dc * Kc);

    for (int t = tid; t < WELEMS; t += NTHREADS)
        wl[t / NBc][t % NBc] = w[(size_t)dk * WELEMS + t];
    if (tid < COc * Sc)
        bl[tid] = bias[(size_t)dk * (COc * Sc) + tid];
    __syncthreads();

    const int l0  = tid * JT;
    const int gl0 = lbase + l0;
    const int s0  = seg_of(gl0);
    const int s7  = seg_of(gl0 + JT - 1);

    const float* xb  = x + (size_t)bdk * CIc * Lc;
    const float* xi0 = xb + gl0;
    const float* xi1 = xb + Lc + gl0;

    // ---- both ci windows up front: xa_i[m] = x[i][gl0-8+m], m in [0,24)
    // 12 independent global_load_dwordx4 in flight (max MLP per wave)
    float xa0[WIN], xa1[WIN];
    if (gl0 >= 8 && gl0 + 16 <= Lc) {
#pragma unroll
        for (int m = 0; m < WIN / 4; ++m)
            *(f32x4*)&xa0[4 * m] = *(const f32x4*)(xi0 - 8 + 4 * m);
#pragma unroll
        for (int m = 0; m < WIN / 4; ++m)
            *(f32x4*)&xa1[4 * m] = *(const f32x4*)(xi1 - 8 + 4 * m);
    } else {
        // row edges (2 threads per bdk row), exec-masked, bounds-clamped
#pragma unroll
        for (int m = 0; m < WIN; ++m) {
            int l = gl0 - 8 + m;
            bool ok = (l >= 0 && l < Lc);
            xa0[m] = ok ? xi0[m - 8] : 0.0f;
            xa1[m] = ok ? xi1[m - 8] : 0.0f;
        }
    }

    float acc[COc][JT];
#pragma unroll
    for (int o = 0; o < COc; ++o)
#pragma unroll
        for (int j = 0; j < JT; ++j)
            acc[o][j] = bl[o * Sc + s0];

    // ---- main FMA block, uniform segment s0; weights as per-f LDS broadcast reads ----
#pragma unroll
    for (int i = 0; i < CIc; ++i) {
        const float* wr0 = &wl[(0 * CIc + i) * Sc + s0][0];
        const float* wr1 = &wl[(1 * CIc + i) * Sc + s0][0];
#pragma unroll
        for (int f = 0; f < NBc; ++f) {
            float wa = wr0[f];   // ds_read broadcast (wave-uniform s0 except at boundary: 2-way, free)
            float wb = wr1[f];
#pragma unroll
            for (int j = 0; j < JT; ++j) {
                float xv = (i == 0) ? xa0[j + f + 1] : xa1[j + f + 1];
                acc[0][j] = fmaf(wa, xv, acc[0][j]);
                acc[1][j] = fmaf(wb, xv, acc[1][j]);
            }
        }
    }

    // ---- fixup: segment-boundary threads (<=7 per bdk row), all indices static ----
    if (s7 != s0) {
        const int jstart = 499 * s7 - gl0;   // in [1, JT-1]
        const float b0 = bl[0 * Sc + s7];
        const float b1 = bl[1 * Sc + s7];
#pragma unroll
        for (int j = 0; j < JT; ++j) {
            if (j >= jstart) {
                float a0 = b0, a1 = b1;
#pragma unroll
                for (int i = 0; i < CIc; ++i) {
#pragma unroll
                    for (int f = 0; f < NBc; ++f) {
                        float xv = (i == 0) ? xa0[j + f + 1] : xa1[j + f + 1];
                        a0 = fmaf(wl[(0 * CIc + i) * Sc + s7][f], xv, a0);
                        a1 = fmaf(wl[(1 * CIc + i) * Sc + s7][f], xv, a1);
                    }
                }
                acc[0][j] = a0;
                acc[1][j] = a1;
            }
        }
    }

    // ---- store: 4 nontemporal dwordx4 ----
    float* ob = out + (size_t)bdk * COc * Lc + gl0;
#pragma unroll
    for (int o = 0; o < COc; ++o) {
        f32x4 v0 = { acc[o][0], acc[o][1], acc[o][2], acc[o][3] };
        f32x4 v1 = { acc[o][4], acc[o][5], acc[o][6], acc[o][7] };
        __builtin_nontemporal_store(v0, (f32x4*)(ob + (size_t)o * Lc));
        __builtin_nontemporal_store(v1, (f32x4*)(ob + (size_t)o * Lc + 4));
    }
}

extern "C" void kernel_launch(void* const* d_in, const int* in_sizes, int n_in,
                              void* d_out, int out_size, void* d_ws, size_t ws_size,
                              hipStream_t stream) {
    const float* x    = (const float*)d_in[0];
    const float* w    = (const float*)d_in[1];
    const float* bias = (const float*)d_in[2];
    float* out        = (float*)d_out;

    dim3 grid(Lc / TILE, Bc * Dc * Kc);   // 2 x 1024 blocks
    cde_bcr_kernel<<<grid, NTHREADS, 0, stream>>>(x, w, bias, out);
}

// Round 10
// 18.774 us; speedup vs baseline: 2.5899x; 2.5899x over previous
//
#include <hip/hip_runtime.h>
#include <stdint.h>

// Problem constants: B,D,K,CI,CO,L,NB,P,S = 4,32,8,2,2,4096,15,7,8
constexpr int Bc  = 4;
constexpr int Dc  = 32;
constexpr int Kc  = 8;
constexpr int CIc = 2;
constexpr int COc = 2;
constexpr int Lc  = 4096;
constexpr int NBc = 15;
constexpr int Sc  = 8;

constexpr int NTHREADS = 256;
constexpr int JT       = 4;                  // outputs per thread per co per tile
constexpr int TILE     = NTHREADS * JT;      // 1024
constexpr int NTILES   = Lc / TILE;          // 4 tiles -> whole row per block
constexpr int WELEMS   = COc * CIc * Sc * NBc;  // 480

typedef float f32x4 __attribute__((ext_vector_type(4)));
typedef const __attribute__((address_space(1))) float* gas1_t;  // global
typedef __attribute__((address_space(3))) float* las3_t;        // LDS

// seg(l) = min(l/499, 7)
__device__ __forceinline__ int seg_of(int l) {
    int s = l / 499;
    return s > 7 ? 7 : s;
}

__global__ __launch_bounds__(NTHREADS) void cde_bcr_kernel(
    const float* __restrict__ x,     // [B][D][K][CI][L]
    const float* __restrict__ w,     // [D][K][CO][CI][S][1][NB]
    const float* __restrict__ bias,  // [D][K][CO][S][1]
    float* __restrict__ out)         // [B][D][K][CO][L]
{
    // whole x row staged: xs[i][8 + l] = x[i][l]; halos [0,8) and [8+Lc,16+Lc) are zeros
    __shared__ __align__(16) float xs[CIc][Lc + 16];          // 32.9 KB
    __shared__ __align__(16) float wl[COc * CIc * Sc][16];    // 2 KB
    __shared__ float bl[COc * Sc];

    const int tid  = threadIdx.x;
    const int lane = tid & 63;
    const int wid  = tid >> 6;
    const int bdk  = blockIdx.x;             // ((b*D + d)*K + k), 1024 blocks
    const int dk   = bdk % (Dc * Kc);

    // ---- fire-and-forget: whole row direct HBM->LDS, zero VGPR cost (m97 width=16) ----
    // LDS dest must be wave-uniform base + lane*16 (m104): base has no lane term,
    // global src per-lane matches base_global + lane*16 -> linear, correct.
    const float* xrow = x + (size_t)bdk * CIc * Lc;
#pragma unroll
    for (int i = 0; i < CIc; ++i) {
#pragma unroll
        for (int q = 0; q < 4; ++q) {        // 4 sweeps x 1024 floats per ci
            const float* g = xrow + (size_t)i * Lc + q * 1024 + wid * 256 + lane * 4;
            float* lp = &xs[i][8 + q * 1024 + wid * 256];   // wave-uniform
            __builtin_amdgcn_global_load_lds((gas1_t)g, (las3_t)lp, 16, 0, 0);
        }
    }

    // ---- weights + bias (regular staging) ----
    for (int t = tid; t < WELEMS; t += NTHREADS)
        wl[t / NBc][t % NBc] = w[(size_t)dk * WELEMS + t];
    if (tid < COc * Sc)
        bl[tid] = bias[(size_t)dk * (COc * Sc) + tid];

    // ---- zero halos (row ends pad with 0) ----
    if (tid < 2 * 16) {
        int i = tid >> 4, e = tid & 15;
        int idx = (e < 8) ? e : (Lc + e);    // [0,8) and [Lc+8, Lc+16)
        xs[i][idx] = 0.0f;
    }

    __syncthreads();   // compiler emits vmcnt(0) drain: all gload_lds landed

    const float* wbase = &wl[0][0];

#pragma unroll
    for (int t = 0; t < NTILES; ++t) {
        const int gl0 = t * TILE + tid * JT;
        const int s0  = seg_of(gl0);
        const int s3  = seg_of(gl0 + JT - 1);

        // windows: xa_i[m] = x[i][gl0-8+m] = xs[i][gl0+m], m in [0,20)
        // ds_read_b128 at 16B lane stride: contiguous 1KB/wave -> conflict-free
        float xa0[20], xa1[20];
#pragma unroll
        for (int m = 0; m < 5; ++m) {
            *(f32x4*)&xa0[4 * m] = *(const f32x4*)&xs[0][gl0 + 4 * m];
            *(f32x4*)&xa1[4 * m] = *(const f32x4*)&xs[1][gl0 + 4 * m];
        }

        float acc[COc][JT];
#pragma unroll
        for (int o = 0; o < COc; ++o)
#pragma unroll
            for (int j = 0; j < JT; ++j)
                acc[o][j] = bl[o * Sc + s0];

#pragma unroll
        for (int i = 0; i < CIc; ++i) {
            float wa[16], wb[16];
#pragma unroll
            for (int m = 0; m < 4; ++m) {
                *(f32x4*)&wa[4 * m] = *(const f32x4*)&wl[(0 * CIc + i) * Sc + s0][4 * m];
                *(f32x4*)&wb[4 * m] = *(const f32x4*)&wl[(1 * CIc + i) * Sc + s0][4 * m];
            }
#pragma unroll
            for (int f = 0; f < NBc; ++f) {
#pragma unroll
                for (int j = 0; j < JT; ++j) {
                    float xv = (i == 0) ? xa0[j + f + 1] : xa1[j + f + 1];
                    acc[0][j] = fmaf(wa[f], xv, acc[0][j]);
                    acc[1][j] = fmaf(wb[f], xv, acc[1][j]);
                }
            }
        }

        // fixup: segment-boundary threads, all register indices static
        if (s3 != s0) {
            const int jstart = 499 * s3 - gl0;   // in [1, JT-1]
            const float b0 = bl[0 * Sc + s3];
            const float b1 = bl[1 * Sc + s3];
#pragma unroll
            for (int j = 0; j < JT; ++j) {
                if (j >= jstart) {
                    float a0 = b0, a1 = b1;
#pragma unroll
                    for (int i = 0; i < CIc; ++i) {
#pragma unroll
                        for (int f = 0; f < NBc; ++f) {
                            float xv = (i == 0) ? xa0[j + f + 1] : xa1[j + f + 1];
                            a0 = fmaf(wl[(0 * CIc + i) * Sc + s3][f], xv, a0);
                            a1 = fmaf(wl[(1 * CIc + i) * Sc + s3][f], xv, a1);
                        }
                    }
                    acc[0][j] = a0;
                    acc[1][j] = a1;
                }
            }
        }

        // store: 2 nontemporal dwordx4 per tile (dense per wave)
        float* ob = out + (size_t)bdk * COc * Lc + gl0;
        f32x4 v0 = { acc[0][0], acc[0][1], acc[0][2], acc[0][3] };
        f32x4 v1 = { acc[1][0], acc[1][1], acc[1][2], acc[1][3] };
        __builtin_nontemporal_store(v0, (f32x4*)(ob));
        __builtin_nontemporal_store(v1, (f32x4*)(ob + Lc));
    }
    (void)wbase;
}

extern "C" void kernel_launch(void* const* d_in, const int* in_sizes, int n_in,
                              void* d_out, int out_size, void* d_ws, size_t ws_size,
                              hipStream_t stream) {
    const float* x    = (const float*)d_in[0];
    const float* w    = (const float*)d_in[1];
    const float* bias = (const float*)d_in[2];
    float* out        = (float*)d_out;

    // 1024 blocks = full-grid resident (4 blocks/CU by LDS), zero tail
    cde_bcr_kernel<<<dim3(Bc * Dc * Kc), NTHREADS, 0, stream>>>(x, w, bias, out);
}